// Round 2
// baseline (641.394 us; speedup 1.0000x reference)
//
#include <hip/hip_runtime.h>
#include <cmath>

#define BB 4
#define NN 5
#define CC 64
#define HH 96
#define WW 288
#define PP (HH*WW)       // 27648 pixels per plane
#define QP (PP/4)        // 6912  float4-quads per plane
#define BP (BB*PP)       // 110592
#define BQ (BP/4)        // 27648

// ---------------------------------------------------------------------------
// Structure (round 2): NO transpose, NO LDS anywhere.
//   PART  : x1 + x0 mask partials, pure float4 streaming. grid (108, 8).
//   KC    : combine partials -> scores -> conf -> binary premask.
//   KP    : 3x3 max-pool (SAME).
//   FUSE  : warp+attention directly from x0's native [b][n][c][p] layout.
//           4 lanes/pixel, scalar gathers. Affine theta ~ identity, so taps
//           for consecutive pixels are ~consecutive addresses -> coalesced
//           through L1/L2. Pass1 (dots) + pass2 (output) re-reads hit L3
//           (x0 = 141.6 MB < 256 MB).
// Buffers:
//   ws path  (ws >= 29.2 MB): dpart1/dpart0/premask/pooled all in d_ws;
//            inputs pristine; KF writes d_out only.
//   fallback: dpart1+dpart0 = d_out (exactly 64*BP floats);
//            premask/pooled = x1 (dead after PART reads it).
// Harness restores inputs before every launch (verified in prior session).
// ---------------------------------------------------------------------------

static __device__ __forceinline__ float sigmoidf_(float x) {
    return 1.0f / (1.0f + expf(-x));
}
static __device__ __forceinline__ float4 f4zero() {
    return make_float4(0.f, 0.f, 0.f, 0.f);
}
static __device__ __forceinline__ void fma4s(float4& a, float s, const float4& v) {
    a.x += s * v.x; a.y += s * v.y; a.z += s * v.z; a.w += s * v.w;
}
static __device__ __forceinline__ void fma44(float4& a, const float4& s, const float4& v) {
    a.x += s.x * v.x; a.y += s.y * v.y; a.z += s.z * v.z; a.w += s.w * v.w;
}
// softmax(4 dots)-weighted mlp -> sigmoid score (reference _frame_score math)
static __device__ __forceinline__ float score4(const float* dd, const float* mm, float bias) {
    float s0 = dd[0]*0.125f, s1 = dd[1]*0.125f, s2 = dd[2]*0.125f, s3 = dd[3]*0.125f;
    float mx = fmaxf(fmaxf(s0, s1), fmaxf(s2, s3));
    float e0 = expf(s0-mx), e1 = expf(s1-mx), e2 = expf(s2-mx), e3 = expf(s3-mx);
    float inv = 1.0f / (e0+e1+e2+e3);
    float z = (e0*mm[0] + e1*mm[1] + e2*mm[2] + e3*mm[3]) * inv + bias;
    return sigmoidf_(z);
}

static __device__ __forceinline__ void theta_load(
    const float* __restrict__ pmat, int b, int n,
    float& t00, float& t01, float& t02, float& t10, float& t11, float& t12)
{
    const float* m = pmat + ((size_t)(b * NN + 0) * NN + n) * 16;
    t00 = m[0];
    t01 = m[1] * ((float)HH / (float)WW);
    t02 = m[3] * (float)(2.0 / (4.0 * 0.4 * (double)WW));
    t10 = m[4] * ((float)WW / (float)HH);
    t11 = m[5];
    t12 = m[7] * (float)(2.0 / (4.0 * 0.4 * (double)HH));
}

// ---------------------------------------------------------------------------
// PART body: mask partials for one source buffer, float4 streaming (p-major).
// dst[(seg*8+j)*BQ + q]: j=0..3 dot_k, j=4..7 mw_k (k=j%4+1).
// Summation structure per pixel: serial over 16 ch within seg, segs combined
// serially in KC -- identical rounding structure to the verified session.
// ---------------------------------------------------------------------------
static __device__ __forceinline__ void part_body(
    int q, int seg,
    const float4* __restrict__ src, const float* __restrict__ mlp_w,
    float4* __restrict__ dst)
{
    int b  = q / QP;
    int qp = q - b * QP;
    const float4* base = src + (size_t)b * (NN*CC*QP) + qp;

    float4 d[4] = {f4zero(), f4zero(), f4zero(), f4zero()};
    float4 m[4] = {f4zero(), f4zero(), f4zero(), f4zero()};
    #pragma unroll 4
    for (int ci = 0; ci < 16; ci++) {
        int c = seg * 16 + ci;
        float4 e  = base[(size_t)c * QP];                    // frame 0 (ego)
        float  wc = mlp_w[c];
        #pragma unroll
        for (int k = 1; k < NN; k++) {
            float4 v = base[((size_t)k * CC + c) * QP];
            fma44(d[k-1], e, v);
            fma4s(m[k-1], wc, v);
        }
    }
    #pragma unroll
    for (int j = 0; j < 4; j++) {
        dst[((size_t)seg * 8 + j)     * BQ + q] = d[j];
        dst[((size_t)seg * 8 + 4 + j) * BQ + q] = m[j];
    }
}

// grid (BQ/256, 8): y = 0..3 -> x1 seg y, y = 4..7 -> x0 seg y-4.
__global__ __launch_bounds__(256) void part_kernel(
    const float4* __restrict__ x0, const float4* __restrict__ x1,
    const float* __restrict__ mlp_w,
    float4* __restrict__ dpart0, float4* __restrict__ dpart1)
{
    int q    = blockIdx.x * 256 + threadIdx.x;   // [0, BQ)
    int seg8 = blockIdx.y;                        // 0..7
    if (seg8 < 4) part_body(q, seg8,     x1, mlp_w, dpart1);
    else          part_body(q, seg8 - 4, x0, mlp_w, dpart0);
}

// ---------------------------------------------------------------------------
// KC: combine x0/x1 partials -> sigmoid scores -> conf -> binary pre-mask.
// grid 108 (one thread per pixel-quad). Both sources segmented identically.
// ---------------------------------------------------------------------------
__global__ __launch_bounds__(256) void comb_kernel(
    const float4* __restrict__ dpart0, const float4* __restrict__ dpart1,
    const float* __restrict__ mlp_b, float4* __restrict__ premask)
{
    int q = blockIdx.x * 256 + threadIdx.x;
    float bias = mlp_b[0];

    float4 d0[8], d1[8];
    #pragma unroll
    for (int j = 0; j < 8; j++) {
        float4 s0 = f4zero(), s1 = f4zero();
        #pragma unroll
        for (int seg = 0; seg < 4; seg++) {
            float4 v0 = dpart0[((size_t)seg * 8 + j) * BQ + q];
            float4 v1 = dpart1[((size_t)seg * 8 + j) * BQ + q];
            s0.x += v0.x; s0.y += v0.y; s0.z += v0.z; s0.w += v0.w;
            s1.x += v1.x; s1.y += v1.y; s1.z += v1.z; s1.w += v1.w;
        }
        d0[j] = s0;
        d1[j] = s1;
    }

    const float W0 = 0.6224593312018546f, W1 = 0.3775406687981454f;
    float4 res;
    #pragma unroll
    for (int kcomp = 0; kcomp < 4; kcomp++) {
        float dd0[4], mm0[4], dd1[4], mm1[4];
        #pragma unroll
        for (int j = 0; j < 4; j++) {
            dd0[j] = ((const float*)&d0[j])[kcomp];
            mm0[j] = ((const float*)&d0[4+j])[kcomp];
            dd1[j] = ((const float*)&d1[j])[kcomp];
            mm1[j] = ((const float*)&d1[4+j])[kcomp];
        }
        float sc0 = score4(dd0, mm0, bias);
        float sc1 = score4(dd1, mm1, bias);
        float conf = W0 * sc0 + W1 * sc1;
        ((float*)&res)[kcomp] = (conf > 0.5f) ? 1.f : 0.f;
    }
    premask[q] = res;
}

// ---------------------------------------------------------------------------
// KP: 3x3 max-pool (SAME), float4. grid 108.
// ---------------------------------------------------------------------------
__global__ __launch_bounds__(256) void pool_kernel(
    const float* __restrict__ pre, float4* __restrict__ pooled)
{
    int q  = blockIdx.x * 256 + threadIdx.x;
    int b  = q / QP;
    int qp = q - b * QP;
    int p0 = qp * 4;
    int h  = p0 / WW;
    int w0 = p0 - h * WW;
    const float* pb = pre + (size_t)b * PP;
    float m[4] = {0.f, 0.f, 0.f, 0.f};
    #pragma unroll
    for (int dy = -1; dy <= 1; dy++) {
        int y = h + dy;
        if (y < 0 || y >= HH) continue;
        const float* row = pb + y * WW;
        float c_[6];
        float4 mid = *(const float4*)(row + w0);
        c_[0] = (w0 > 0) ? row[w0 - 1] : 0.f;
        c_[1] = mid.x; c_[2] = mid.y; c_[3] = mid.z; c_[4] = mid.w;
        c_[5] = (w0 + 4 < WW) ? row[w0 + 4] : 0.f;
        #pragma unroll
        for (int j = 0; j < 4; j++)
            m[j] = fmaxf(m[j], fmaxf(c_[j], fmaxf(c_[j+1], c_[j+2])));
    }
    pooled[q] = make_float4(m[0], m[1], m[2], m[3]);
}

// ---------------------------------------------------------------------------
// FUSE: warp + attention + output, gathering directly from x0 [b][n][c][p].
// 4 lanes per pixel (each lane owns 16 channels). Per pixel: 20 (frame,tap)
// pairs precomputed (offset + combined weight incl. validity & pooled mask).
// Pass 1: accumulate dots over own channels, 4-lane shfl reduce, softmax.
// Pass 2: recompute warped values (taps are L1/L3-hot) and emit output.
// Zero-weight taps skip the load (bit-identical: acc += 0).
// grid BP/64 = 1728 blocks x 256 thr, chunked XCD swizzle (1728%8==0).
// ---------------------------------------------------------------------------
__global__ __launch_bounds__(256) void fuse_gather_kernel(
    const float* __restrict__ x0, const float* __restrict__ pmat,
    const float* __restrict__ pooled, float* __restrict__ out)
{
    int bid = blockIdx.x;
    int swz = (bid & 7) * (BP/64/8) + (bid >> 3);   // chunked XCD swizzle
    int pix0 = swz * 64;
    int b  = pix0 / PP;                  // block-uniform
    int p0 = pix0 - b * PP;
    int lane4 = threadIdx.x & 3;         // channel group (16 ch)
    int pi    = threadIdx.x >> 2;        // 0..63
    int p = p0 + pi;
    int h = p / WW;
    int w = p - h * WW;

    float gx = -1.0f + 2.0f * (float)w / (float)(WW - 1);
    float gy = -1.0f + 2.0f * (float)h / (float)(HH - 1);
    const float* poolb = pooled + (size_t)b * PP;

    int   off[NN][4];
    float wgt[NN][4];
    #pragma unroll
    for (int n = 0; n < NN; n++) {
        float t00, t01, t02, t10, t11, t12;
        theta_load(pmat, b, n, t00, t01, t02, t10, t11, t12);
        float g0 = t00 * gx + t01 * gy + t02;
        float g1 = t10 * gx + t11 * gy + t12;
        float fx = (g0 + 1.0f) * 0.5f * (float)(WW - 1);
        float fy = (g1 + 1.0f) * 0.5f * (float)(HH - 1);
        float x0f = floorf(fx), y0f = floorf(fy);
        float wx = fx - x0f, wy = fy - y0f;
        float bw[4] = { (1.f - wx) * (1.f - wy), wx * (1.f - wy),
                        (1.f - wx) * wy,         wx * wy };
        #pragma unroll
        for (int t = 0; t < 4; t++) {
            float xx = (t & 1) ? (x0f + 1.0f) : x0f;
            float yy = (t >> 1) ? (y0f + 1.0f) : y0f;
            int xi = min(max((int)xx, 0), WW - 1);
            int yi = min(max((int)yy, 0), HH - 1);
            float valid = (yy >= 0.0f && yy <= (float)(HH - 1) &&
                           xx >= 0.0f && xx <= (float)(WW - 1)) ? 1.0f : 0.0f;
            off[n][t] = yi * WW + xi;
            float mk = (n == 0) ? 1.0f : poolb[off[n][t]];
            wgt[n][t] = bw[t] * valid * mk;
        }
    }

    // per-lane channel base: frame n, channel ci -> base + (n*CC + ci)*PP
    const float* base = x0 + ((size_t)b * NN * CC + (size_t)lane4 * 16) * PP;

    // ---- pass 1: dots over this lane's 16 channels ----
    float dt[NN] = {0.f, 0.f, 0.f, 0.f, 0.f};
    #pragma unroll 2
    for (int ci = 0; ci < 16; ci++) {
        const float* cb = base + (size_t)ci * PP;
        float v0 = 0.f;
        #pragma unroll
        for (int t = 0; t < 4; t++)
            if (wgt[0][t] != 0.f) v0 += wgt[0][t] * cb[off[0][t]];
        dt[0] += v0 * v0;
        #pragma unroll
        for (int n = 1; n < NN; n++) {
            const float* fb = cb + (size_t)n * CC * PP;
            float v = 0.f;
            #pragma unroll
            for (int t = 0; t < 4; t++)
                if (wgt[n][t] != 0.f) v += wgt[n][t] * fb[off[n][t]];
            dt[n] += v0 * v;
        }
    }
    // reduce over the 4 lanes of this pixel (lanes 4*pi .. 4*pi+3)
    #pragma unroll
    for (int n = 0; n < NN; n++) {
        dt[n] += __shfl_xor(dt[n], 1, 64);
        dt[n] += __shfl_xor(dt[n], 2, 64);
    }

    // softmax over 5 (redundant per lane)
    float s[NN], attn[NN];
    float mx = -INFINITY;
    #pragma unroll
    for (int n = 0; n < NN; n++) { s[n] = dt[n] * 0.125f; mx = fmaxf(mx, s[n]); }
    float sum = 0.f;
    #pragma unroll
    for (int n = 0; n < NN; n++) { attn[n] = expf(s[n] - mx); sum += attn[n]; }
    float inv = 1.0f / sum;
    #pragma unroll
    for (int n = 0; n < NN; n++) attn[n] *= inv;

    // ---- pass 2: recompute warped values, weight by attn, store ----
    #pragma unroll 2
    for (int ci = 0; ci < 16; ci++) {
        const float* cb = base + (size_t)ci * PP;
        float o = 0.f;
        #pragma unroll
        for (int n = 0; n < NN; n++) {
            const float* fb = cb + (size_t)n * CC * PP;
            float v = 0.f;
            #pragma unroll
            for (int t = 0; t < 4; t++)
                if (wgt[n][t] != 0.f) v += wgt[n][t] * fb[off[n][t]];
            o += attn[n] * v;
        }
        int c = lane4 * 16 + ci;
        out[((size_t)(b * CC + c)) * PP + p] = o;
    }
}

// ---------------------------------------------------------------------------
extern "C" void kernel_launch(void* const* d_in, const int* in_sizes, int n_in,
                              void* d_out, int out_size, void* d_ws, size_t ws_size,
                              hipStream_t stream) {
    float*       x0    = (float*)d_in[0];
    float*       x1    = (float*)d_in[1];
    const float* pmat  = (const float*)d_in[2];
    const float* mlp_w = (const float*)d_in[3];
    const float* mlp_b = (const float*)d_in[4];
    float* out = (float*)d_out;

    float4* x0f4 = (float4*)x0;
    float4* x1f4 = (float4*)x1;

    const size_t need_ws = (size_t)66 * BP * sizeof(float);   // 29.2 MB
    bool use_ws = (d_ws != nullptr) && (ws_size >= need_ws);

    float *dpart1_f, *dpart0_f, *pre_f, *pool_f;
    if (use_ws) {
        float* ws = (float*)d_ws;
        dpart1_f = ws;                       // 32*BP floats
        dpart0_f = ws + (size_t)32 * BP;     // 32*BP floats
        pre_f    = ws + (size_t)64 * BP;     // BP floats
        pool_f   = ws + (size_t)65 * BP;     // BP floats
    } else {
        dpart1_f = out;                      // d_out = 64*BP floats exactly
        dpart0_f = out + (size_t)32 * BP;
        pre_f    = x1;                       // x1 dead after PART reads it
        pool_f   = x1 + (size_t)BP;
    }
    float4* dpart1 = (float4*)dpart1_f;
    float4* dpart0 = (float4*)dpart0_f;
    float4* pre_4  = (float4*)pre_f;
    float4* pool_4 = (float4*)pool_f;

    dim3 blk(256);
    part_kernel      <<<dim3(BQ/256, 8), blk, 0, stream>>>(x0f4, x1f4, mlp_w, dpart0, dpart1);
    comb_kernel      <<<dim3(BQ/256),    blk, 0, stream>>>(dpart0, dpart1, mlp_b, pre_4);
    pool_kernel      <<<dim3(BQ/256),    blk, 0, stream>>>(pre_f, pool_4);
    fuse_gather_kernel<<<dim3(BP/64),    blk, 0, stream>>>(x0, pmat, pool_f, out);
}

// Round 3
// 570.596 us; speedup vs baseline: 1.1241x; 1.1241x over previous
//
#include <hip/hip_runtime.h>
#include <cmath>

#define BB 4
#define NN 5
#define CC 64
#define HH 96
#define WW 288
#define PP (HH*WW)       // 27648 pixels per plane
#define QP (PP/4)        // 6912  float4-quads per plane
#define BP (BB*PP)       // 110592
#define BQ (BP/4)        // 27648

// ---------------------------------------------------------------------------
// Structure (round 3): NO transpose, NO LDS, latency-tolerant gathers.
//   PART : mask partials, k-pair split: grid (108, 16) = 1728 blocks.
//          y = seg(4) x khalf(2) x src(2); 48 loads/thread, 4 accum f4.
//   KC   : combine partials -> scores -> conf -> binary premask. (unchanged)
//   KP   : 3x3 max-pool (SAME). (unchanged)
//   FUSE : 16 lanes/pixel (4 ch each), ONE pass, wv[5] in regs, native x0
//          layout. All value loads UNCONDITIONAL (mask applied as a
//          multiplier after a separate batched mask-load phase) -> no
//          control-dependent chains, ~16 independent loads in flight per
//          frame. grid BP/16 = 6912 blocks, chunked XCD swizzle.
// Buffers (same plan as round 2):
//   ws path  (ws >= 29.2 MB): dpart0/1, premask, pooled in d_ws.
//   fallback: dpart0/1 = d_out (64*BP floats exactly);
//             premask/pooled = x1 (fully consumed by PART before KC writes).
// Harness restores inputs before every launch (verified in prior session).
// ---------------------------------------------------------------------------

static __device__ __forceinline__ float sigmoidf_(float x) {
    return 1.0f / (1.0f + expf(-x));
}
static __device__ __forceinline__ float4 f4zero() {
    return make_float4(0.f, 0.f, 0.f, 0.f);
}
static __device__ __forceinline__ void fma4s(float4& a, float s, const float4& v) {
    a.x += s * v.x; a.y += s * v.y; a.z += s * v.z; a.w += s * v.w;
}
static __device__ __forceinline__ void fma44(float4& a, const float4& s, const float4& v) {
    a.x += s.x * v.x; a.y += s.y * v.y; a.z += s.z * v.z; a.w += s.w * v.w;
}
static __device__ __forceinline__ float dot4(const float4& a, const float4& b) {
    return a.x*b.x + a.y*b.y + a.z*b.z + a.w*b.w;
}
// softmax(4 dots)-weighted mlp -> sigmoid score (reference _frame_score math)
static __device__ __forceinline__ float score4(const float* dd, const float* mm, float bias) {
    float s0 = dd[0]*0.125f, s1 = dd[1]*0.125f, s2 = dd[2]*0.125f, s3 = dd[3]*0.125f;
    float mx = fmaxf(fmaxf(s0, s1), fmaxf(s2, s3));
    float e0 = expf(s0-mx), e1 = expf(s1-mx), e2 = expf(s2-mx), e3 = expf(s3-mx);
    float inv = 1.0f / (e0+e1+e2+e3);
    float z = (e0*mm[0] + e1*mm[1] + e2*mm[2] + e3*mm[3]) * inv + bias;
    return sigmoidf_(z);
}

static __device__ __forceinline__ void theta_load(
    const float* __restrict__ pmat, int b, int n,
    float& t00, float& t01, float& t02, float& t10, float& t11, float& t12)
{
    const float* m = pmat + ((size_t)(b * NN + 0) * NN + n) * 16;
    t00 = m[0];
    t01 = m[1] * ((float)HH / (float)WW);
    t02 = m[3] * (float)(2.0 / (4.0 * 0.4 * (double)WW));
    t10 = m[4] * ((float)WW / (float)HH);
    t11 = m[5];
    t12 = m[7] * (float)(2.0 / (4.0 * 0.4 * (double)HH));
}

// ---------------------------------------------------------------------------
// PART body: partials for frames k0, k0+1 of one seg of one source.
// dst[(seg*8+j)*BQ + q]: j=0..3 dot_k (k=j+1), j=4..7 mw_k.
// Per-k accumulation order (ci = 0..15 sequential) identical to the
// verified round-2 kernel -> identical mask bits.
// ---------------------------------------------------------------------------
static __device__ __forceinline__ void part_body_k2(
    int q, int seg, int k0,
    const float4* __restrict__ src, const float* __restrict__ mlp_w,
    float4* __restrict__ dst)
{
    int b  = q / QP;
    int qp = q - b * QP;
    const float4* base = src + (size_t)b * (NN*CC*QP) + qp;

    float4 d0 = f4zero(), d1 = f4zero();
    float4 m0 = f4zero(), m1 = f4zero();
    #pragma unroll 2
    for (int ci = 0; ci < 16; ci++) {
        int c = seg * 16 + ci;
        float4 e  = base[(size_t)c * QP];                    // frame 0 (ego)
        float  wc = mlp_w[c];
        float4 v0 = base[((size_t)k0       * CC + c) * QP];
        float4 v1 = base[((size_t)(k0 + 1) * CC + c) * QP];
        fma44(d0, e, v0);  fma4s(m0, wc, v0);
        fma44(d1, e, v1);  fma4s(m1, wc, v1);
    }
    int j0 = k0 - 1;
    dst[((size_t)seg * 8 + j0    ) * BQ + q] = d0;
    dst[((size_t)seg * 8 + j0 + 1) * BQ + q] = d1;
    dst[((size_t)seg * 8 + 4 + j0    ) * BQ + q] = m0;
    dst[((size_t)seg * 8 + 4 + j0 + 1) * BQ + q] = m1;
}

// grid (BQ/256, 16): y = seg*4 + khalf*2 + src.
__global__ __launch_bounds__(256) void part_kernel(
    const float4* __restrict__ x0, const float4* __restrict__ x1,
    const float* __restrict__ mlp_w,
    float4* __restrict__ dpart0, float4* __restrict__ dpart1)
{
    int q     = blockIdx.x * 256 + threadIdx.x;   // [0, BQ)
    int y     = blockIdx.y;                        // 0..15
    int seg   = y >> 2;
    int khalf = (y >> 1) & 1;
    int srcid = y & 1;
    int k0    = 1 + 2 * khalf;                     // 1 or 3
    if (srcid) part_body_k2(q, seg, k0, x1, mlp_w, dpart1);
    else       part_body_k2(q, seg, k0, x0, mlp_w, dpart0);
}

// ---------------------------------------------------------------------------
// KC: combine x0/x1 partials -> sigmoid scores -> conf -> binary pre-mask.
// grid 108 (one thread per pixel-quad).
// ---------------------------------------------------------------------------
__global__ __launch_bounds__(256) void comb_kernel(
    const float4* __restrict__ dpart0, const float4* __restrict__ dpart1,
    const float* __restrict__ mlp_b, float4* __restrict__ premask)
{
    int q = blockIdx.x * 256 + threadIdx.x;
    float bias = mlp_b[0];

    float4 d0[8], d1[8];
    #pragma unroll
    for (int j = 0; j < 8; j++) {
        float4 s0 = f4zero(), s1 = f4zero();
        #pragma unroll
        for (int seg = 0; seg < 4; seg++) {
            float4 v0 = dpart0[((size_t)seg * 8 + j) * BQ + q];
            float4 v1 = dpart1[((size_t)seg * 8 + j) * BQ + q];
            s0.x += v0.x; s0.y += v0.y; s0.z += v0.z; s0.w += v0.w;
            s1.x += v1.x; s1.y += v1.y; s1.z += v1.z; s1.w += v1.w;
        }
        d0[j] = s0;
        d1[j] = s1;
    }

    const float W0 = 0.6224593312018546f, W1 = 0.3775406687981454f;
    float4 res;
    #pragma unroll
    for (int kcomp = 0; kcomp < 4; kcomp++) {
        float dd0[4], mm0[4], dd1[4], mm1[4];
        #pragma unroll
        for (int j = 0; j < 4; j++) {
            dd0[j] = ((const float*)&d0[j])[kcomp];
            mm0[j] = ((const float*)&d0[4+j])[kcomp];
            dd1[j] = ((const float*)&d1[j])[kcomp];
            mm1[j] = ((const float*)&d1[4+j])[kcomp];
        }
        float sc0 = score4(dd0, mm0, bias);
        float sc1 = score4(dd1, mm1, bias);
        float conf = W0 * sc0 + W1 * sc1;
        ((float*)&res)[kcomp] = (conf > 0.5f) ? 1.f : 0.f;
    }
    premask[q] = res;
}

// ---------------------------------------------------------------------------
// KP: 3x3 max-pool (SAME), float4. grid 108.
// ---------------------------------------------------------------------------
__global__ __launch_bounds__(256) void pool_kernel(
    const float* __restrict__ pre, float4* __restrict__ pooled)
{
    int q  = blockIdx.x * 256 + threadIdx.x;
    int b  = q / QP;
    int qp = q - b * QP;
    int p0 = qp * 4;
    int h  = p0 / WW;
    int w0 = p0 - h * WW;
    const float* pb = pre + (size_t)b * PP;
    float m[4] = {0.f, 0.f, 0.f, 0.f};
    #pragma unroll
    for (int dy = -1; dy <= 1; dy++) {
        int y = h + dy;
        if (y < 0 || y >= HH) continue;
        const float* row = pb + y * WW;
        float c_[6];
        float4 mid = *(const float4*)(row + w0);
        c_[0] = (w0 > 0) ? row[w0 - 1] : 0.f;
        c_[1] = mid.x; c_[2] = mid.y; c_[3] = mid.z; c_[4] = mid.w;
        c_[5] = (w0 + 4 < WW) ? row[w0 + 4] : 0.f;
        #pragma unroll
        for (int j = 0; j < 4; j++)
            m[j] = fmaxf(m[j], fmaxf(c_[j], fmaxf(c_[j+1], c_[j+2])));
    }
    pooled[q] = make_float4(m[0], m[1], m[2], m[3]);
}

// ---------------------------------------------------------------------------
// FUSE: warp + attention + output, native x0 [b][n][c][p] layout.
// 16 lanes per pixel, each lane owns channels cq*4..cq*4+3.
// Phase 1: compute all 20 tap offsets + bilinear*valid weights (no loads).
// Phase 2: 16 pooled-mask loads, batched, then folded into wgt.
// Phase 3: per frame, 16 UNCONDITIONAL value loads (independent addresses,
//          no branches) -> combine into wv[n] (4 floats/lane).
// Phase 4: dots via 16-lane shfl reduce, softmax(5), output (same math &
//          order as the verified round-0 kernel).
// grid BP/16 = 6912 blocks x 256 thr, chunked XCD swizzle (6912 % 8 == 0).
// ---------------------------------------------------------------------------
__global__ __launch_bounds__(256) void fuse_kernel(
    const float* __restrict__ x0, const float* __restrict__ pmat,
    const float* __restrict__ pooled, float* __restrict__ out)
{
    int bid = blockIdx.x;
    int swz = (bid & 7) * (BP/16/8) + (bid >> 3);   // chunked XCD swizzle
    int pix0 = swz * 16;
    int b  = pix0 / PP;                  // block-uniform
    int p0 = pix0 - b * PP;
    int pi = threadIdx.x >> 4;           // 0..15 pixel within block
    int cq = threadIdx.x & 15;           // channel quad
    int p  = p0 + pi;
    int h  = p / WW;
    int w  = p - h * WW;

    float gx = -1.0f + 2.0f * (float)w / (float)(WW - 1);
    float gy = -1.0f + 2.0f * (float)h / (float)(HH - 1);
    const float* poolb = pooled + (size_t)b * PP;

    // ---- phase 1: offsets + bilinear*valid weights (pure ALU) ----
    int   off[NN][4];
    float wgt[NN][4];
    #pragma unroll
    for (int n = 0; n < NN; n++) {
        float t00, t01, t02, t10, t11, t12;
        theta_load(pmat, b, n, t00, t01, t02, t10, t11, t12);
        float g0 = t00 * gx + t01 * gy + t02;
        float g1 = t10 * gx + t11 * gy + t12;
        float fx = (g0 + 1.0f) * 0.5f * (float)(WW - 1);
        float fy = (g1 + 1.0f) * 0.5f * (float)(HH - 1);
        float x0f = floorf(fx), y0f = floorf(fy);
        float wx = fx - x0f, wy = fy - y0f;
        float bw[4] = { (1.f - wx) * (1.f - wy), wx * (1.f - wy),
                        (1.f - wx) * wy,         wx * wy };
        #pragma unroll
        for (int t = 0; t < 4; t++) {
            float xx = (t & 1) ? (x0f + 1.0f) : x0f;
            float yy = (t >> 1) ? (y0f + 1.0f) : y0f;
            int xi = min(max((int)xx, 0), WW - 1);
            int yi = min(max((int)yy, 0), HH - 1);
            float valid = (yy >= 0.0f && yy <= (float)(HH - 1) &&
                           xx >= 0.0f && xx <= (float)(WW - 1)) ? 1.0f : 0.0f;
            off[n][t] = yi * WW + xi;
            wgt[n][t] = bw[t] * valid;
        }
    }

    // ---- phase 2: batched mask loads (independent of value loads) ----
    float mk[NN-1][4];
    #pragma unroll
    for (int n = 1; n < NN; n++)
        #pragma unroll
        for (int t = 0; t < 4; t++)
            mk[n-1][t] = poolb[off[n][t]];
    #pragma unroll
    for (int n = 1; n < NN; n++)
        #pragma unroll
        for (int t = 0; t < 4; t++)
            wgt[n][t] *= mk[n-1][t];

    // ---- phase 3: unconditional value gathers, one pass ----
    const float* bb = x0 + ((size_t)b * NN * CC + (size_t)cq * 4) * PP;
    float4 wv[NN];
    #pragma unroll
    for (int n = 0; n < NN; n++) {
        const float* fr = bb + (size_t)n * CC * PP;
        float v[4][4];                       // [tap][channel j]
        #pragma unroll
        for (int t = 0; t < 4; t++)
            #pragma unroll
            for (int j = 0; j < 4; j++)
                v[t][j] = fr[(size_t)j * PP + off[n][t]];
        float4 acc = f4zero();
        #pragma unroll
        for (int t = 0; t < 4; t++) {
            acc.x += wgt[n][t] * v[t][0];
            acc.y += wgt[n][t] * v[t][1];
            acc.z += wgt[n][t] * v[t][2];
            acc.w += wgt[n][t] * v[t][3];
        }
        wv[n] = acc;
    }

    // ---- phase 4: dots (16-lane reduce), softmax, output ----
    float dt[NN];
    #pragma unroll
    for (int n = 0; n < NN; n++) dt[n] = dot4(wv[0], wv[n]);
    #pragma unroll
    for (int n = 0; n < NN; n++) {
        #pragma unroll
        for (int msk = 1; msk < 16; msk <<= 1)
            dt[n] += __shfl_xor(dt[n], msk, 16);
    }

    float s[NN], attn[NN];
    float mx = -INFINITY;
    #pragma unroll
    for (int n = 0; n < NN; n++) { s[n] = dt[n] * 0.125f; mx = fmaxf(mx, s[n]); }
    float sum = 0.f;
    #pragma unroll
    for (int n = 0; n < NN; n++) { attn[n] = expf(s[n] - mx); sum += attn[n]; }
    float inv = 1.0f / sum;

    float4 o = f4zero();
    #pragma unroll
    for (int n = 0; n < NN; n++) fma4s(o, attn[n] * inv, wv[n]);

    size_t ob = ((size_t)(b * CC + cq * 4)) * PP + p;
    out[ob]                = o.x;
    out[ob + (size_t)PP]   = o.y;
    out[ob + (size_t)2*PP] = o.z;
    out[ob + (size_t)3*PP] = o.w;
}

// ---------------------------------------------------------------------------
extern "C" void kernel_launch(void* const* d_in, const int* in_sizes, int n_in,
                              void* d_out, int out_size, void* d_ws, size_t ws_size,
                              hipStream_t stream) {
    float*       x0    = (float*)d_in[0];
    float*       x1    = (float*)d_in[1];
    const float* pmat  = (const float*)d_in[2];
    const float* mlp_w = (const float*)d_in[3];
    const float* mlp_b = (const float*)d_in[4];
    float* out = (float*)d_out;

    float4* x0f4 = (float4*)x0;
    float4* x1f4 = (float4*)x1;

    const size_t need_ws = (size_t)66 * BP * sizeof(float);   // 29.2 MB
    bool use_ws = (d_ws != nullptr) && (ws_size >= need_ws);

    float *dpart1_f, *dpart0_f, *pre_f, *pool_f;
    if (use_ws) {
        float* ws = (float*)d_ws;
        dpart1_f = ws;                       // 32*BP floats
        dpart0_f = ws + (size_t)32 * BP;     // 32*BP floats
        pre_f    = ws + (size_t)64 * BP;     // BP floats
        pool_f   = ws + (size_t)65 * BP;     // BP floats
    } else {
        dpart1_f = out;                      // d_out = 64*BP floats exactly
        dpart0_f = out + (size_t)32 * BP;
        pre_f    = x1;                       // x1 dead after PART reads it
        pool_f   = x1 + (size_t)BP;
    }
    float4* dpart1 = (float4*)dpart1_f;
    float4* dpart0 = (float4*)dpart0_f;
    float4* pre_4  = (float4*)pre_f;
    float4* pool_4 = (float4*)pool_f;

    dim3 blk(256);
    part_kernel <<<dim3(BQ/256, 16), blk, 0, stream>>>(x0f4, x1f4, mlp_w, dpart0, dpart1);
    comb_kernel <<<dim3(BQ/256),     blk, 0, stream>>>(dpart0, dpart1, mlp_b, pre_4);
    pool_kernel <<<dim3(BQ/256),     blk, 0, stream>>>(pre_f, pool_4);
    fuse_kernel <<<dim3(BP/16),      blk, 0, stream>>>(x0, pmat, pool_f, out);
}

// Round 4
// 440.032 us; speedup vs baseline: 1.4576x; 1.2967x over previous
//
#include <hip/hip_runtime.h>
#include <cmath>

#define BB 4
#define NN 5
#define CC 64
#define HH 96
#define WW 288
#define PP (HH*WW)       // 27648 pixels per plane
#define QP (PP/4)        // 6912  float4-quads per plane
#define BP (BB*PP)       // 110592
#define BQ (BP/4)        // 27648
#define TP 65            // LDS transpose pitch (floats), 65%32==1 -> <=2-way

// ---------------------------------------------------------------------------
// Structure (round 4): best measured component per stage.
//   PART  : native-layout mask partials, k-pair split, FULL unroll (one big
//           vmcnt batch of 48 loads), XCD-chunked work swizzle so the 16
//           slices sharing a q-window (and thus ego planes) share an L2.
//   TRANS : pure 64px x 64ch LDS transpose x0 -> x0t [b][n][p][c].
//           1 sync, 16.6 KB LDS, grid (432, 20). No dot fusion.
//   KC/KP : unchanged (verified).
//   FUSE  : r0's vector-gather body: 16 lanes/pixel, 20 UNCONDITIONAL 16B
//           loads from x0t, masks batched & folded into weights, + XCD
//           chunk swizzle + block-uniform b.
// Buffers:
//   ws path (>= 170.8 MB): x0t, dpart0/1, premask, pooled all in d_ws.
//   fallback: x0t = x1 (read by PART first), dpart = d_out (exact fit),
//             premask/pooled = x0[0:2BP] (x0 fully read by TRANS first).
//   Launch order part -> trans -> comb -> pool -> fuse makes both paths safe.
// Harness restores inputs before every launch (verified in prior rounds).
// ---------------------------------------------------------------------------

static __device__ __forceinline__ float sigmoidf_(float x) {
    return 1.0f / (1.0f + expf(-x));
}
static __device__ __forceinline__ float4 f4zero() {
    return make_float4(0.f, 0.f, 0.f, 0.f);
}
static __device__ __forceinline__ void fma4s(float4& a, float s, const float4& v) {
    a.x += s * v.x; a.y += s * v.y; a.z += s * v.z; a.w += s * v.w;
}
static __device__ __forceinline__ void fma44(float4& a, const float4& s, const float4& v) {
    a.x += s.x * v.x; a.y += s.y * v.y; a.z += s.z * v.z; a.w += s.w * v.w;
}
static __device__ __forceinline__ float dot4(const float4& a, const float4& b) {
    return a.x*b.x + a.y*b.y + a.z*b.z + a.w*b.w;
}
// softmax(4 dots)-weighted mlp -> sigmoid score (reference _frame_score math)
static __device__ __forceinline__ float score4(const float* dd, const float* mm, float bias) {
    float s0 = dd[0]*0.125f, s1 = dd[1]*0.125f, s2 = dd[2]*0.125f, s3 = dd[3]*0.125f;
    float mx = fmaxf(fmaxf(s0, s1), fmaxf(s2, s3));
    float e0 = expf(s0-mx), e1 = expf(s1-mx), e2 = expf(s2-mx), e3 = expf(s3-mx);
    float inv = 1.0f / (e0+e1+e2+e3);
    float z = (e0*mm[0] + e1*mm[1] + e2*mm[2] + e3*mm[3]) * inv + bias;
    return sigmoidf_(z);
}

static __device__ __forceinline__ void theta_load(
    const float* __restrict__ pmat, int b, int n,
    float& t00, float& t01, float& t02, float& t10, float& t11, float& t12)
{
    const float* m = pmat + ((size_t)(b * NN + 0) * NN + n) * 16;
    t00 = m[0];
    t01 = m[1] * ((float)HH / (float)WW);
    t02 = m[3] * (float)(2.0 / (4.0 * 0.4 * (double)WW));
    t10 = m[4] * ((float)WW / (float)HH);
    t11 = m[5];
    t12 = m[7] * (float)(2.0 / (4.0 * 0.4 * (double)HH));
}

// ---------------------------------------------------------------------------
// PART: mask partials for frames k0,k0+1 of one 16-ch seg of one source.
// Flat grid 1728; work = XCD-chunked swizzle; work = qblk*16 + slice so all
// 16 slices of a q-window (sharing ego planes) run on the same XCD.
// dst[(seg*8+j)*BQ + q]: j=0..3 dot_k (k=j+1), j=4..7 mw_k.
// Per-k accumulation order (ci sequential) identical to verified r3.
// ---------------------------------------------------------------------------
__global__ __launch_bounds__(256) void part_kernel(
    const float4* __restrict__ x0, const float4* __restrict__ x1,
    const float* __restrict__ mlp_w,
    float4* __restrict__ dpart0, float4* __restrict__ dpart1)
{
    int bid  = blockIdx.x;                       // 0..1727
    int work = (bid & 7) * (1728/8) + (bid >> 3);
    int qblk  = work >> 4;                       // 0..107
    int slice = work & 15;
    int seg   = slice >> 2;
    int khalf = (slice >> 1) & 1;
    int srcid = slice & 1;
    int k0    = 1 + 2 * khalf;                   // 1 or 3
    int q     = qblk * 256 + threadIdx.x;        // [0, BQ)

    const float4* src = srcid ? x1 : x0;
    float4*       dst = srcid ? dpart1 : dpart0;

    int b  = q / QP;
    int qp = q - b * QP;
    const float4* base = src + (size_t)b * (NN*CC*QP) + qp;

    float4 d0 = f4zero(), d1 = f4zero();
    float4 m0 = f4zero(), m1 = f4zero();
    #pragma unroll
    for (int ci = 0; ci < 16; ci++) {
        int c = seg * 16 + ci;
        float4 e  = base[(size_t)c * QP];                    // frame 0 (ego)
        float  wc = mlp_w[c];
        float4 v0 = base[((size_t)k0       * CC + c) * QP];
        float4 v1 = base[((size_t)(k0 + 1) * CC + c) * QP];
        fma44(d0, e, v0);  fma4s(m0, wc, v0);
        fma44(d1, e, v1);  fma4s(m1, wc, v1);
    }
    int j0 = k0 - 1;
    dst[((size_t)seg * 8 + j0        ) * BQ + q] = d0;
    dst[((size_t)seg * 8 + j0 + 1    ) * BQ + q] = d1;
    dst[((size_t)seg * 8 + 4 + j0    ) * BQ + q] = m0;
    dst[((size_t)seg * 8 + 4 + j0 + 1) * BQ + q] = m1;
}

// ---------------------------------------------------------------------------
// TRANS: pure transpose x0 [plane][p] -> x0t [plane][p][c], plane = b*NN+n.
// 64px x 64ch tile per block, one __syncthreads, 16.6 KB LDS.
// grid (PP/64 = 432, BB*NN = 20).
// ---------------------------------------------------------------------------
__global__ __launch_bounds__(256) void transpose_kernel(
    const float4* __restrict__ xin, float4* __restrict__ x0t)
{
    __shared__ float T[64 * TP];
    int t     = threadIdx.x;
    int tile  = blockIdx.x;          // 0..431
    int plane = blockIdx.y;          // 0..19  (== b*NN + n)

    {
        int c  = t >> 2;             // channel row 0..63
        int pq = t & 3;              // 16-px group
        const float4* src = xin + ((size_t)plane * CC + c) * QP + tile * 16 + pq * 4;
        float4 r[4];
        #pragma unroll
        for (int j = 0; j < 4; j++) r[j] = src[j];
        #pragma unroll
        for (int j = 0; j < 4; j++) {
            int col = pq * 16 + j * 4;
            T[c*TP + col+0] = r[j].x;
            T[c*TP + col+1] = r[j].y;
            T[c*TP + col+2] = r[j].z;
            T[c*TP + col+3] = r[j].w;
        }
    }
    __syncthreads();
    {
        int pix = t >> 2;            // pixel 0..63
        int cg  = t & 3;             // 16-ch group
        float a[16];
        #pragma unroll
        for (int j = 0; j < 16; j++) a[j] = T[(cg*16 + j)*TP + pix];
        float4* dst = x0t + ((size_t)plane * PP + tile * 64 + pix) * 16 + cg * 4;
        #pragma unroll
        for (int jj = 0; jj < 4; jj++)
            dst[jj] = make_float4(a[jj*4+0], a[jj*4+1], a[jj*4+2], a[jj*4+3]);
    }
}

// ---------------------------------------------------------------------------
// KC: combine x0/x1 partials -> sigmoid scores -> conf -> binary pre-mask.
// grid 108. (verified)
// ---------------------------------------------------------------------------
__global__ __launch_bounds__(256) void comb_kernel(
    const float4* __restrict__ dpart0, const float4* __restrict__ dpart1,
    const float* __restrict__ mlp_b, float4* __restrict__ premask)
{
    int q = blockIdx.x * 256 + threadIdx.x;
    float bias = mlp_b[0];

    float4 d0[8], d1[8];
    #pragma unroll
    for (int j = 0; j < 8; j++) {
        float4 s0 = f4zero(), s1 = f4zero();
        #pragma unroll
        for (int seg = 0; seg < 4; seg++) {
            float4 v0 = dpart0[((size_t)seg * 8 + j) * BQ + q];
            float4 v1 = dpart1[((size_t)seg * 8 + j) * BQ + q];
            s0.x += v0.x; s0.y += v0.y; s0.z += v0.z; s0.w += v0.w;
            s1.x += v1.x; s1.y += v1.y; s1.z += v1.z; s1.w += v1.w;
        }
        d0[j] = s0;
        d1[j] = s1;
    }

    const float W0 = 0.6224593312018546f, W1 = 0.3775406687981454f;
    float4 res;
    #pragma unroll
    for (int kcomp = 0; kcomp < 4; kcomp++) {
        float dd0[4], mm0[4], dd1[4], mm1[4];
        #pragma unroll
        for (int j = 0; j < 4; j++) {
            dd0[j] = ((const float*)&d0[j])[kcomp];
            mm0[j] = ((const float*)&d0[4+j])[kcomp];
            dd1[j] = ((const float*)&d1[j])[kcomp];
            mm1[j] = ((const float*)&d1[4+j])[kcomp];
        }
        float sc0 = score4(dd0, mm0, bias);
        float sc1 = score4(dd1, mm1, bias);
        float conf = W0 * sc0 + W1 * sc1;
        ((float*)&res)[kcomp] = (conf > 0.5f) ? 1.f : 0.f;
    }
    premask[q] = res;
}

// ---------------------------------------------------------------------------
// KP: 3x3 max-pool (SAME), float4. grid 108. (verified)
// ---------------------------------------------------------------------------
__global__ __launch_bounds__(256) void pool_kernel(
    const float* __restrict__ pre, float4* __restrict__ pooled)
{
    int q  = blockIdx.x * 256 + threadIdx.x;
    int b  = q / QP;
    int qp = q - b * QP;
    int p0 = qp * 4;
    int h  = p0 / WW;
    int w0 = p0 - h * WW;
    const float* pb = pre + (size_t)b * PP;
    float m[4] = {0.f, 0.f, 0.f, 0.f};
    #pragma unroll
    for (int dy = -1; dy <= 1; dy++) {
        int y = h + dy;
        if (y < 0 || y >= HH) continue;
        const float* row = pb + y * WW;
        float c_[6];
        float4 mid = *(const float4*)(row + w0);
        c_[0] = (w0 > 0) ? row[w0 - 1] : 0.f;
        c_[1] = mid.x; c_[2] = mid.y; c_[3] = mid.z; c_[4] = mid.w;
        c_[5] = (w0 + 4 < WW) ? row[w0 + 4] : 0.f;
        #pragma unroll
        for (int j = 0; j < 4; j++)
            m[j] = fmaxf(m[j], fmaxf(c_[j], fmaxf(c_[j+1], c_[j+2])));
    }
    pooled[q] = make_float4(m[0], m[1], m[2], m[3]);
}

// ---------------------------------------------------------------------------
// FUSE: warp + attention + output from x0t ([p][c] layout).
// 16 lanes/pixel (lane = channel quad). All 20 value loads are 16B and
// UNCONDITIONAL; pooled-mask loads batched first and folded into weights.
// Chunked XCD swizzle (6912 % 8 == 0), block-uniform b.
// grid BP/16 = 6912 x 256 thr.
// ---------------------------------------------------------------------------
__global__ __launch_bounds__(256) void fuse_kernel(
    const float4* __restrict__ x0t, const float* __restrict__ pmat,
    const float* __restrict__ pooled, float* __restrict__ out)
{
    int bid = blockIdx.x;
    int swz = (bid & 7) * (BP/16/8) + (bid >> 3);   // chunked XCD swizzle
    int pix0 = swz * 16;
    int b  = pix0 / PP;                  // block-uniform
    int p0 = pix0 - b * PP;
    int pi = threadIdx.x >> 4;           // pixel within block
    int cq = threadIdx.x & 15;           // channel quad
    int p  = p0 + pi;
    int h  = p / WW;
    int w  = p - h * WW;

    float gx = -1.0f + 2.0f * (float)w / (float)(WW - 1);
    float gy = -1.0f + 2.0f * (float)h / (float)(HH - 1);
    const float* poolb = pooled + (size_t)b * PP;

    // ---- phase 1: offsets + bilinear*valid weights (pure ALU) ----
    int   off[NN][4];
    float wgt[NN][4];
    #pragma unroll
    for (int n = 0; n < NN; n++) {
        float t00, t01, t02, t10, t11, t12;
        theta_load(pmat, b, n, t00, t01, t02, t10, t11, t12);
        float g0 = t00 * gx + t01 * gy + t02;
        float g1 = t10 * gx + t11 * gy + t12;
        float fx = (g0 + 1.0f) * 0.5f * (float)(WW - 1);
        float fy = (g1 + 1.0f) * 0.5f * (float)(HH - 1);
        float x0f = floorf(fx), y0f = floorf(fy);
        float wx = fx - x0f, wy = fy - y0f;
        float bw[4] = { (1.f - wx) * (1.f - wy), wx * (1.f - wy),
                        (1.f - wx) * wy,         wx * wy };
        #pragma unroll
        for (int t = 0; t < 4; t++) {
            float xx = (t & 1) ? (x0f + 1.0f) : x0f;
            float yy = (t >> 1) ? (y0f + 1.0f) : y0f;
            int xi = min(max((int)xx, 0), WW - 1);
            int yi = min(max((int)yy, 0), HH - 1);
            float valid = (yy >= 0.0f && yy <= (float)(HH - 1) &&
                           xx >= 0.0f && xx <= (float)(WW - 1)) ? 1.0f : 0.0f;
            off[n][t] = yi * WW + xi;
            wgt[n][t] = bw[t] * valid;
        }
    }

    // ---- phase 2: batched mask loads, fold into weights ----
    float mk[NN-1][4];
    #pragma unroll
    for (int n = 1; n < NN; n++)
        #pragma unroll
        for (int t = 0; t < 4; t++)
            mk[n-1][t] = poolb[off[n][t]];
    #pragma unroll
    for (int n = 1; n < NN; n++)
        #pragma unroll
        for (int t = 0; t < 4; t++)
            wgt[n][t] *= mk[n-1][t];

    // ---- phase 3: unconditional 16B gathers, one pass ----
    const float4* bb = x0t + (size_t)b * NN * PP * 16;
    float4 wv[NN];
    #pragma unroll
    for (int n = 0; n < NN; n++) {
        const float4* fr = bb + (size_t)n * PP * 16;
        float4 v0 = fr[(size_t)off[n][0] * 16 + cq];
        float4 v1 = fr[(size_t)off[n][1] * 16 + cq];
        float4 v2 = fr[(size_t)off[n][2] * 16 + cq];
        float4 v3 = fr[(size_t)off[n][3] * 16 + cq];
        float4 acc = f4zero();
        fma4s(acc, wgt[n][0], v0);
        fma4s(acc, wgt[n][1], v1);
        fma4s(acc, wgt[n][2], v2);
        fma4s(acc, wgt[n][3], v3);
        wv[n] = acc;
    }

    // ---- phase 4: dots (16-lane shfl reduce), softmax, output ----
    float dt[NN];
    #pragma unroll
    for (int n = 0; n < NN; n++) dt[n] = dot4(wv[0], wv[n]);
    #pragma unroll
    for (int n = 0; n < NN; n++) {
        #pragma unroll
        for (int msk = 1; msk < 16; msk <<= 1)
            dt[n] += __shfl_xor(dt[n], msk, 16);
    }

    float s[NN], attn[NN];
    float mx = -INFINITY;
    #pragma unroll
    for (int n = 0; n < NN; n++) { s[n] = dt[n] * 0.125f; mx = fmaxf(mx, s[n]); }
    float sum = 0.f;
    #pragma unroll
    for (int n = 0; n < NN; n++) { attn[n] = expf(s[n] - mx); sum += attn[n]; }
    float inv = 1.0f / sum;

    float4 o = f4zero();
    #pragma unroll
    for (int n = 0; n < NN; n++) fma4s(o, attn[n] * inv, wv[n]);

    size_t ob = ((size_t)(b * CC + cq * 4)) * PP + p;
    out[ob]                = o.x;
    out[ob + (size_t)PP]   = o.y;
    out[ob + (size_t)2*PP] = o.z;
    out[ob + (size_t)3*PP] = o.w;
}

// ---------------------------------------------------------------------------
extern "C" void kernel_launch(void* const* d_in, const int* in_sizes, int n_in,
                              void* d_out, int out_size, void* d_ws, size_t ws_size,
                              hipStream_t stream) {
    float*       x0    = (float*)d_in[0];
    float*       x1    = (float*)d_in[1];
    const float* pmat  = (const float*)d_in[2];
    const float* mlp_w = (const float*)d_in[3];
    const float* mlp_b = (const float*)d_in[4];
    float* out = (float*)d_out;

    float4* x0f4 = (float4*)x0;
    float4* x1f4 = (float4*)x1;

    const size_t x0t_floats = (size_t)BB * NN * PP * CC;          // 35.4 M
    const size_t need_ws = (x0t_floats + (size_t)66 * BP) * sizeof(float); // 170.8 MB
    bool use_ws = (d_ws != nullptr) && (ws_size >= need_ws);

    float *x0t_f, *dpart0_f, *dpart1_f, *pre_f, *pool_f;
    if (use_ws) {
        float* ws = (float*)d_ws;
        x0t_f    = ws;                                  // 141.6 MB
        dpart0_f = ws + x0t_floats;                     // 32*BP floats
        dpart1_f = ws + x0t_floats + (size_t)32 * BP;   // 32*BP floats
        pre_f    = ws + x0t_floats + (size_t)64 * BP;   // BP floats
        pool_f   = ws + x0t_floats + (size_t)65 * BP;   // BP floats
    } else {
        x0t_f    = x1;                       // x1 fully read by PART first
        dpart0_f = out;                      // d_out = 64*BP floats exactly
        dpart1_f = out + (size_t)32 * BP;
        pre_f    = x0;                       // x0 fully read by TRANS first
        pool_f   = x0 + (size_t)BP;
    }
    float4* x0t    = (float4*)x0t_f;
    float4* dpart0 = (float4*)dpart0_f;
    float4* dpart1 = (float4*)dpart1_f;
    float4* pre_4  = (float4*)pre_f;
    float4* pool_4 = (float4*)pool_f;

    dim3 blk(256);
    part_kernel      <<<dim3(1728),        blk, 0, stream>>>(x0f4, x1f4, mlp_w, dpart0, dpart1);
    transpose_kernel <<<dim3(PP/64, BB*NN),blk, 0, stream>>>(x0f4, x0t);
    comb_kernel      <<<dim3(BQ/256),      blk, 0, stream>>>(dpart0, dpart1, mlp_b, pre_4);
    pool_kernel      <<<dim3(BQ/256),      blk, 0, stream>>>(pre_f, pool_4);
    fuse_kernel      <<<dim3(BP/16),       blk, 0, stream>>>(x0t, pmat, pool_f, out);
}